// Round 5
// baseline (365.570 us; speedup 1.0000x reference)
//
#include <hip/hip_runtime.h>
#include <math.h>

// Problem constants
#define B_    64
#define C_    80
#define DE_   300
#define DE1_  1024
#define J_    4000
#define S_    100
#define KP_   40      // J/S
#define FDIM_ 2048

// Workspace layout (float offsets)
#define WS_FEAT   0          // [64,2048]           131072
#define WS_B1     131072     // [1024,80]            81920
#define WS_B2     212992     // [1024,80]            81920
#define WS_AW     294912     // [80,80]               6400
#define WS_T1     307712     // [80,1024]            81920
#define WS_H      389632     // [80,1024]            81920
#define WS_HH     471552     // [80,1024]            81920
#define WS_X      553472     // [80,2048]           163840
#define WS_IMG    717312     // [64,4000]           256000
#define WS_CLS    973312     // [80,4000]           320000
#define WS_POOL   1293312    // [64,80,40]          204800

typedef __bf16 bf16x8 __attribute__((ext_vector_type(8)));
typedef float  f32x4  __attribute__((ext_vector_type(4)));

__device__ __forceinline__ bf16x8 cvt_bf16x8(float4 a, float4 b) {
    bf16x8 r;
    r[0] = (__bf16)a.x; r[1] = (__bf16)a.y; r[2] = (__bf16)a.z; r[3] = (__bf16)a.w;
    r[4] = (__bf16)b.x; r[5] = (__bf16)b.y; r[6] = (__bf16)b.z; r[7] = (__bf16)b.w;
    return r;
}

// Explicitly software-pipelined MFMA tile, B^T layout (W row-major [N,K]).
// Depth-4 register pipeline: ~24 float4 loads in flight per wave.
template<int KSTEPS>
__device__ __forceinline__ void mfma_bt_pipe(const float* __restrict__ A0,
                                             const float* __restrict__ B0,
                                             const float* __restrict__ B1,
                                             f32x4& acc0, f32x4& acc1) {
    constexpr int D = 4;
    float4 ra[D][2], rb0[D][2], rb1[D][2];
    #pragma unroll
    for (int p = 0; p < D; ++p) {
        ra[p][0]  = ((const float4*)(A0 + p * 32))[0];
        ra[p][1]  = ((const float4*)(A0 + p * 32))[1];
        rb0[p][0] = ((const float4*)(B0 + p * 32))[0];
        rb0[p][1] = ((const float4*)(B0 + p * 32))[1];
        rb1[p][0] = ((const float4*)(B1 + p * 32))[0];
        rb1[p][1] = ((const float4*)(B1 + p * 32))[1];
    }
    #pragma unroll
    for (int ks = 0; ks < KSTEPS; ++ks) {
        const int slot = ks % D;
        bf16x8 af  = cvt_bf16x8(ra[slot][0],  ra[slot][1]);
        bf16x8 bf0 = cvt_bf16x8(rb0[slot][0], rb0[slot][1]);
        bf16x8 bf1 = cvt_bf16x8(rb1[slot][0], rb1[slot][1]);
        if (ks + D < KSTEPS) {
            ra[slot][0]  = ((const float4*)(A0 + (ks + D) * 32))[0];
            ra[slot][1]  = ((const float4*)(A0 + (ks + D) * 32))[1];
            rb0[slot][0] = ((const float4*)(B0 + (ks + D) * 32))[0];
            rb0[slot][1] = ((const float4*)(B0 + (ks + D) * 32))[1];
            rb1[slot][0] = ((const float4*)(B1 + (ks + D) * 32))[0];
            rb1[slot][1] = ((const float4*)(B1 + (ks + D) * 32))[1];
        }
        acc0 = __builtin_amdgcn_mfma_f32_16x16x32_bf16(af, bf0, acc0, 0, 0, 0);
        acc1 = __builtin_amdgcn_mfma_f32_16x16x32_bf16(af, bf1, acc1, 0, 0, 0);
    }
}

__device__ __forceinline__ void mfma_store_atomic(float* __restrict__ C, int Nst,
                                                  int m0, int n0, int r, int q,
                                                  const f32x4& acc0, const f32x4& acc1) {
    #pragma unroll
    for (int i = 0; i < 4; ++i) {
        int row = m0 + q * 4 + i;
        atomicAdd(&C[(size_t)row * Nst + n0 + r], acc0[i]);
        atomicAdd(&C[(size_t)row * Nst + n0 + 16 + r], acc1[i]);
    }
}

// Per-block inline computation of d[] = rowsum(Aw)^-1/2 into LDS (dsh[80]).
// Aw is 25.6 KB, L2-resident. tid = threadIdx.x, 256 threads.
__device__ __forceinline__ void compute_d(const float* __restrict__ Aw,
                                          float* __restrict__ rs,
                                          float* __restrict__ dsh, int tid) {
    if (tid < 80) rs[tid] = 0.f;
    __syncthreads();
    #pragma unroll
    for (int i2 = tid; i2 < 6400; i2 += 256)
        atomicAdd(&rs[i2 / 80], Aw[i2]);
    __syncthreads();
    if (tid < 80) {
        float dv = rsqrtf(rs[tid]);
        if (!isfinite(dv)) dv = 0.f;
        dsh[tid] = dv;
    }
    __syncthreads();
}

// ================================================================ launch 1
// [0,640): b1b2 | [640,960): t1 full-K | [960,3875): init | [3875,36643): maxpool
__global__ void mega1(const float* __restrict__ feature, float* __restrict__ feat,
                      const float* __restrict__ inp,
                      const float* __restrict__ Wb1, const float* __restrict__ bb1,
                      const float* __restrict__ Wb2, const float* __restrict__ bb2,
                      float* __restrict__ b1, float* __restrict__ b2,
                      const float* __restrict__ Wg1, float* __restrict__ t1,
                      float* __restrict__ x, float* __restrict__ Aw,
                      const float* __restrict__ bimg, float* __restrict__ img,
                      const float* __restrict__ bcls, float* __restrict__ cls) {
    int bid = blockIdx.x;
    int tid = threadIdx.x;
    if (bid < 640) {
        // ---- b1/b2 sigmoid
        int idx = bid * 256 + tid;            // 0 .. 163839
        int which = idx >= 81920;
        int r = which ? idx - 81920 : idx;
        int o = r / 80, c = r % 80;
        const float* W = which ? Wb2 : Wb1;
        const float* bb = which ? bb2 : bb1;
        float acc = bb[o];
        const float* wrow = W + o * 300;
        #pragma unroll 10
        for (int k = 0; k < 300; ++k)
            acc = fmaf(wrow[k], inp[k * 80 + c], acc);
        (which ? b2 : b1)[r] = 1.0f / (1.0f + expf(-acc));
        return;
    }
    if (bid < 960) {
        // ---- t1 = inp @ Wg1 (full K, no atomics)
        int idx = (bid - 640) * 256 + tid;    // 0..81919
        int m = idx >> 10, n = idx & 1023;
        float acc = 0.f;
        const float* arow = inp + m * 300;
        #pragma unroll 10
        for (int k = 0; k < 300; ++k)
            acc = fmaf(arow[k], Wg1[k * 1024 + n], acc);
        t1[idx] = acc;
        return;
    }
    if (bid < 3875) {
        // ---- init: Aw=I(6400) | x=0(163840) | img=bimg(256000) | cls=bcls(320000)
        int idx = (bid - 960) * 256 + tid;
        if (idx < 6400) {
            int i = idx / 80, j = idx % 80;
            Aw[idx] = (i == j) ? 1.0f : 0.0f;
            return;
        }
        idx -= 6400;
        if (idx < 163840) { x[idx] = 0.0f; return; }
        idx -= 163840;
        if (idx < 256000) { img[idx] = bimg[idx % 4000]; return; }
        idx -= 256000;
        if (idx < 320000) { cls[idx] = bcls[idx % 4000]; }
        return;
    }
    // ---- maxpool: one wave per (b,c)
    int gtid = (bid - 3875) * 256 + tid;
    int wid  = gtid >> 6;                     // 0..131071
    int lane = gtid & 63;
    const float* src = feature + (size_t)wid * 196;
    float v = -INFINITY;
    if (lane < 49) {
        float4 u = ((const float4*)src)[lane];
        v = fmaxf(fmaxf(u.x, u.y), fmaxf(u.z, u.w));
    }
    #pragma unroll
    for (int off = 32; off > 0; off >>= 1)
        v = fmaxf(v, __shfl_down(v, off));
    if (lane == 0) feat[wid] = v;
}

// ================================================================ launch 2
// [0,200): gram split-K8 | [200,1200): img MFMA split-K8 (pipelined)
__global__ void mega2(const float* __restrict__ b1, const float* __restrict__ b2,
                      float* __restrict__ Aw,
                      const float* __restrict__ feat, const float* __restrict__ Wimg,
                      float* __restrict__ img) {
    int bid = blockIdx.x;
    if (bid < 200) {
        int idx = (bid % 25) * 256 + threadIdx.x;   // 0..6399
        int i = idx / 80, j = idx % 80;
        int k0 = (bid / 25) * 128;
        float acc = 0.f;
        #pragma unroll 8
        for (int k = k0; k < k0 + 128; ++k)
            acc = fmaf(b1[k * 80 + i], b2[k * 80 + j], acc);
        atomicAdd(&Aw[idx], acc * (1.0f / 80.0f));
        return;
    }
    // ---- img += feat @ Wimg^T : M=64 (4 waves), n-tile 32, k-chunk 256
    int bid3 = bid - 200;                     // 0..999
    int nt = bid3 % 125, kc = bid3 / 125;
    int w = threadIdx.x >> 6;
    int lane = threadIdx.x & 63;
    int r = lane & 15, q = lane >> 4;
    int n0 = nt * 32, m0 = w * 16, k0 = kc * 256;
    const float* A0 = feat + (size_t)(m0 + r) * 2048 + k0 + q * 8;
    const float* B0 = Wimg + (size_t)(n0 + r) * 2048 + k0 + q * 8;
    const float* B1 = Wimg + (size_t)(n0 + 16 + r) * 2048 + k0 + q * 8;
    f32x4 acc0 = {0.f, 0.f, 0.f, 0.f}, acc1 = {0.f, 0.f, 0.f, 0.f};
    mfma_bt_pipe<8>(A0, B0, B1, acc0, acc1);
    mfma_store_atomic(img, 4000, m0, n0, r, q, acc0, acc1);
}

// ---------------------------------------------------------------- h = leaky(Ahat @ t1), d inline
// 320 blocks x 256; block b owns row m = b>>2, cols (b&3)*256 + tid
__global__ void h_kernel(const float* __restrict__ Aw,
                         const float* __restrict__ t1,
                         float* __restrict__ h) {
    __shared__ float rs[80], dsh[80], ar[80];
    int tid = threadIdx.x;
    int m = blockIdx.x >> 2;
    int n = ((blockIdx.x & 3) << 8) + tid;
    compute_d(Aw, rs, dsh, tid);
    if (tid < 80) ar[tid] = dsh[m] * dsh[tid] * Aw[m * 80 + tid];
    __syncthreads();
    float acc = 0.f;
    #pragma unroll 8
    for (int k = 0; k < 80; ++k)
        acc = fmaf(ar[k], t1[k * 1024 + n], acc);
    h[(size_t)m * 1024 + n] = acc > 0.f ? acc : 0.2f * acc;
}

// ---------------------------------------------------------------- hh = Ahat @ h, d inline
__global__ void hh_kernel(const float* __restrict__ Aw,
                          const float* __restrict__ h,
                          float* __restrict__ hh) {
    __shared__ float rs[80], dsh[80], ar[80];
    int tid = threadIdx.x;
    int m = blockIdx.x >> 2;
    int n = ((blockIdx.x & 3) << 8) + tid;
    compute_d(Aw, rs, dsh, tid);
    if (tid < 80) ar[tid] = dsh[m] * dsh[tid] * Aw[m * 80 + tid];
    __syncthreads();
    float acc = 0.f;
    #pragma unroll 8
    for (int k = 0; k < 80; ++k)
        acc = fmaf(ar[k], h[k * 1024 + n], acc);
    hh[(size_t)m * 1024 + n] = acc;
}

// ---------------------------------------------------------------- x += hh @ Wg2 (MFMA, split-K 4, pipelined)
__global__ __launch_bounds__(320) void gemm_x_mfma(const float* __restrict__ hh,
                                                   const float* __restrict__ Wg2,
                                                   float* __restrict__ x) {
    int w = threadIdx.x >> 6;
    int lane = threadIdx.x & 63;
    int r = lane & 15, q = lane >> 4;
    int n0 = blockIdx.x * 32;
    int k0 = blockIdx.y * 256;
    int m0 = w * 16;

    const float* arow = hh + (size_t)(m0 + r) * 1024 + k0 + q * 8;
    const float* bcol = Wg2 + (size_t)(k0 + q * 8) * 2048 + n0 + r;

    constexpr int D = 4, KS = 8;
    float4 ra[D][2];
    float rb0[D][8], rb1[D][8];
    #pragma unroll
    for (int p = 0; p < D; ++p) {
        ra[p][0] = ((const float4*)(arow + p * 32))[0];
        ra[p][1] = ((const float4*)(arow + p * 32))[1];
        const float* bp = bcol + (size_t)p * 32 * 2048;
        #pragma unroll
        for (int j = 0; j < 8; ++j) {
            rb0[p][j] = bp[(size_t)j * 2048];
            rb1[p][j] = bp[(size_t)j * 2048 + 16];
        }
    }
    f32x4 acc0 = {0.f, 0.f, 0.f, 0.f}, acc1 = {0.f, 0.f, 0.f, 0.f};
    #pragma unroll
    for (int ks = 0; ks < KS; ++ks) {
        const int slot = ks % D;
        bf16x8 af = cvt_bf16x8(ra[slot][0], ra[slot][1]);
        bf16x8 bf0, bf1;
        #pragma unroll
        for (int j = 0; j < 8; ++j) {
            bf0[j] = (__bf16)rb0[slot][j];
            bf1[j] = (__bf16)rb1[slot][j];
        }
        if (ks + D < KS) {
            ra[slot][0] = ((const float4*)(arow + (ks + D) * 32))[0];
            ra[slot][1] = ((const float4*)(arow + (ks + D) * 32))[1];
            const float* bp = bcol + (size_t)(ks + D) * 32 * 2048;
            #pragma unroll
            for (int j = 0; j < 8; ++j) {
                rb0[slot][j] = bp[(size_t)j * 2048];
                rb1[slot][j] = bp[(size_t)j * 2048 + 16];
            }
        }
        acc0 = __builtin_amdgcn_mfma_f32_16x16x32_bf16(af, bf0, acc0, 0, 0, 0);
        acc1 = __builtin_amdgcn_mfma_f32_16x16x32_bf16(af, bf1, acc1, 0, 0, 0);
    }
    mfma_store_atomic(x, 2048, m0, n0, r, q, acc0, acc1);
}

// ---------------------------------------------------------------- cls += x @ Wcls^T (MFMA, split-K 8, pipelined)
__global__ __launch_bounds__(320) void gemm_cls_mfma(const float* __restrict__ x,
                                                     const float* __restrict__ Wcls,
                                                     float* __restrict__ cls) {
    int w = threadIdx.x >> 6;
    int lane = threadIdx.x & 63;
    int r = lane & 15, q = lane >> 4;
    int n0 = blockIdx.x * 32;
    int k0 = blockIdx.y * 256;
    int m0 = w * 16;
    const float* A0 = x    + (size_t)(m0 + r) * 2048 + k0 + q * 8;
    const float* B0 = Wcls + (size_t)(n0 + r) * 2048 + k0 + q * 8;
    const float* B1 = Wcls + (size_t)(n0 + 16 + r) * 2048 + k0 + q * 8;
    f32x4 acc0 = {0.f, 0.f, 0.f, 0.f}, acc1 = {0.f, 0.f, 0.f, 0.f};
    mfma_bt_pipe<8>(A0, B0, B1, acc0, acc1);
    mfma_store_atomic(cls, 4000, m0, n0, r, q, acc0, acc1);
}

// ---------------------------------------------------------------- pool + loss block
// blocks [0,800): pooled | block 800: L_A_loss (from Aw, d inline)
__global__ void pool_loss_kernel(const float* __restrict__ img,
                                 const float* __restrict__ cls,
                                 float* __restrict__ pooled,
                                 const float* __restrict__ Aw,
                                 float* __restrict__ loss_out) {
    int tid = threadIdx.x;
    if (blockIdx.x == 800) {
        __shared__ float rs[80], dsh[80];
        __shared__ float red[256];
        compute_d(Aw, rs, dsh, tid);
        float loss = 0.f;
        for (int idx = tid; idx < 6400; idx += 256) {
            int i = idx / 80, j = idx % 80;
            float ah = dsh[i] * Aw[idx] * dsh[j];
            loss += fabsf(ah - (i == j ? 1.0f : 0.0f));
        }
        red[tid] = loss;
        __syncthreads();
        for (int s = 128; s > 0; s >>= 1) {
            if (tid < s) red[tid] += red[tid + s];
            __syncthreads();
        }
        if (tid == 0) *loss_out = red[0];
        return;
    }
    int idx = blockIdx.x * 256 + tid;     // 0..204799
    int b = idx / 3200;
    int rem = idx % 3200;
    int c = rem / 40, k = rem % 40;
    const float4* ia = (const float4*)(img + (size_t)b * 4000 + k * 100);
    const float4* ca = (const float4*)(cls + (size_t)c * 4000 + k * 100);
    float acc = 0.f;
    #pragma unroll 5
    for (int s = 0; s < 25; ++s) {
        float4 u = ia[s], v = ca[s];
        acc = fmaf(u.x, v.x, acc);
        acc = fmaf(u.y, v.y, acc);
        acc = fmaf(u.z, v.z, acc);
        acc = fmaf(u.w, v.w, acc);
    }
    pooled[(size_t)b * 3200 + c * 40 + k] = acc;
}

// ---------------------------------------------------------------- out: one wave per output
__global__ void out_kernel(const float* __restrict__ pooled,
                           const float* __restrict__ Wml,
                           const float* __restrict__ bml,
                           float* __restrict__ out) {
    int gid = blockIdx.x * 256 + threadIdx.x;
    int wid = gid >> 6;       // 0..5119
    int lane = gid & 63;
    int b = wid / 80, co = wid % 80;
    const float* pr = pooled + (size_t)b * 3200;
    const float* wr = Wml + (size_t)co * 3200;
    float acc = 0.f;
    #pragma unroll 5
    for (int k = lane; k < 3200; k += 64)
        acc = fmaf(pr[k], wr[k], acc);
    #pragma unroll
    for (int off = 32; off > 0; off >>= 1)
        acc += __shfl_down(acc, off);
    if (lane == 0) out[wid] = acc + bml[co];
}

// ---------------------------------------------------------------- launch
extern "C" void kernel_launch(void* const* d_in, const int* in_sizes, int n_in,
                              void* d_out, int out_size, void* d_ws, size_t ws_size,
                              hipStream_t stream) {
    const float* feature = (const float*)d_in[0];
    const float* inp     = (const float*)d_in[1];
    const float* Wb1     = (const float*)d_in[2];
    const float* bb1     = (const float*)d_in[3];
    const float* Wb2     = (const float*)d_in[4];
    const float* bb2     = (const float*)d_in[5];
    const float* Wg1     = (const float*)d_in[6];
    const float* Wg2     = (const float*)d_in[7];
    const float* Wimg    = (const float*)d_in[8];
    const float* bimg    = (const float*)d_in[9];
    const float* Wcls    = (const float*)d_in[10];
    const float* bcls    = (const float*)d_in[11];
    const float* Wml     = (const float*)d_in[12];
    const float* bml     = (const float*)d_in[13];

    float* ws  = (float*)d_ws;
    float* out = (float*)d_out;            // [64,80] then loss at [5120]

    float* feat   = ws + WS_FEAT;
    float* b1     = ws + WS_B1;
    float* b2     = ws + WS_B2;
    float* Aw     = ws + WS_AW;
    float* t1     = ws + WS_T1;
    float* h      = ws + WS_H;
    float* hh     = ws + WS_HH;
    float* x      = ws + WS_X;
    float* img    = ws + WS_IMG;
    float* cls    = ws + WS_CLS;
    float* pooled = ws + WS_POOL;

    mega1<<<36643, 256, 0, stream>>>(feature, feat, inp, Wb1, bb1, Wb2, bb2,
                                     b1, b2, Wg1, t1, x, Aw, bimg, img, bcls, cls);
    mega2<<<1200, 256, 0, stream>>>(b1, b2, Aw, feat, Wimg, img);
    h_kernel<<<320, 256, 0, stream>>>(Aw, t1, h);
    hh_kernel<<<320, 256, 0, stream>>>(Aw, h, hh);
    gemm_x_mfma<<<dim3(64, 4), 320, 0, stream>>>(hh, Wg2, x);
    gemm_cls_mfma<<<dim3(125, 8), 320, 0, stream>>>(x, Wcls, cls);
    pool_loss_kernel<<<801, 256, 0, stream>>>(img, cls, pooled, Aw, out + 5120);
    out_kernel<<<1280, 256, 0, stream>>>(pooled, Wml, bml, out);
}